// Round 1
// baseline (13078.726 us; speedup 1.0000x reference)
//
#include <hip/hip_runtime.h>

#define NB   128
#define TIN  256
#define DIN  64
#define HD   1024
#define G4   4096
#define TOUTC 128
#define DOUTC 128

typedef _Float16 f16x8 __attribute__((ext_vector_type(8)));
typedef float    f32x4 __attribute__((ext_vector_type(4)));

// workspace layout (bytes)
#define FLAGS_OFF 0                         // 32 counters, stride 64B
#define HPP_OFF   4096                      // 2 * 128 * 1024 f16 = 524288
#define HS2_OFF   (4096 + 524288)           // 128*128*1024 f16 = 33554432
#define WLT_OFF   (HS2_OFF + 33554432)      // 128*1024 f16 = 262144

__device__ __forceinline__ float sigm(float z) {
    return 1.0f / (1.0f + __expf(-z));
}
__device__ __forceinline__ float tanh_(float z) {
    float e = __expf(2.0f * z);          // +inf for large z -> 1-0 = 1; 0 for -inf -> -1
    return 1.0f - 2.0f / (e + 1.0f);
}

__global__ void k_init(const float* __restrict__ Wlin, unsigned char* __restrict__ ws)
{
    int tid = blockIdx.x * blockDim.x + threadIdx.x;
    if (tid < 32) ((int*)(ws + FLAGS_OFF))[tid * 16] = 0;
    _Float16* wlt = (_Float16*)(ws + WLT_OFF);
    for (int i = tid; i < DOUTC * HD; i += gridDim.x * blockDim.x) {
        int d = i >> 10, k = i & 1023;
        wlt[i] = (_Float16)Wlin[k * DOUTC + d];   // WlinT[d][k]
    }
}

// Persistent recurrent kernel: 256 WGs x 512 threads, 1 WG/CU.
// group g = batches [32g,32g+32); WG p owns hidden units [16p,16p+16) -> gate cols ct*1024+16p..+15
// wave (r,ks): r = row half (16 batches), ks = K-quarter (256 of 1024). Wh frags live in VGPRs.
__global__ __launch_bounds__(512, 2)
void k_lstm(const float* __restrict__ x,   const float* __restrict__ Wi1,
            const float* __restrict__ Wh1, const float* __restrict__ b1,
            const float* __restrict__ Wi2, const float* __restrict__ Wh2,
            const float* __restrict__ b2,  unsigned char* __restrict__ ws)
{
    int* flags      = (int*)(ws + FLAGS_OFF);
    _Float16* hpp   = (_Float16*)(ws + HPP_OFF);
    _Float16* hs2   = (_Float16*)(ws + HS2_OFF);

    const int tid  = threadIdx.x;
    const int lane = tid & 63;
    const int w    = tid >> 6;
    const int r    = w & 1;
    const int ks   = w >> 1;
    const int gid  = blockIdx.x;
    const int g    = gid >> 6;
    const int p    = gid & 63;
    const int u0   = p << 4;
    const int l15  = lane & 15;
    const int lhi  = lane >> 4;
    const int brow = g * 32 + r * 16 + l15;   // batch row for MFMA operands
    const int kq   = ks << 8;                 // K-quarter base

    __shared__ float parts[2][3][2][4][16][17];   // [parity][ks-1][r][gate][unit][row] 52224B
    __shared__ float xg2s[2][4][16][17];          // [r][gate][unit][row]               8704B

    f16x8 wB[8][4];      // Wh frags: [kk][gate], K-quarter split per wave
    f16x8 wX[2][4];      // Wi1 frags (ks==1 waves only)
    float bias4[4];
    f32x4 cst = {0.f, 0.f, 0.f, 0.f};   // c-state: 4 rows, unit u0+l15 (ks0 waves)

    // ---- load Wh1 fragments into registers ----
    {
        const float* W = Wh1;
        #pragma unroll
        for (int kk = 0; kk < 8; ++kk)
        #pragma unroll
        for (int ct = 0; ct < 4; ++ct) {
            const int col = ct * HD + u0 + l15;
            const int kb  = kq + kk * 32 + lhi * 8;
            f16x8 v;
            #pragma unroll
            for (int e = 0; e < 8; ++e) v[e] = (_Float16)W[(kb + e) * G4 + col];
            wB[kk][ct] = v;
        }
    }
    if (ks == 1) {
        #pragma unroll
        for (int kk = 0; kk < 2; ++kk)
        #pragma unroll
        for (int ct = 0; ct < 4; ++ct) {
            const int col = ct * HD + u0 + l15;
            const int kb  = kk * 32 + lhi * 8;
            f16x8 v;
            #pragma unroll
            for (int e = 0; e < 8; ++e) v[e] = (_Float16)Wi1[(kb + e) * G4 + col];
            wX[kk][ct] = v;
        }
    }
    if (ks == 0) {
        #pragma unroll
        for (int ct = 0; ct < 4; ++ct) bias4[ct] = b1[ct * HD + u0 + l15];
    }

    int* myflag  = &flags[((g * 2 + r) * 4 + ks) * 16];        // what this wave consumes
    int* outflag = &flags[((g * 2 + r) * 4 + (p >> 4)) * 16];  // what ks0 waves produce

    bool dead = false;   // spin bailout latch (anti-hang insurance)

    #pragma unroll 1
    for (int s = 0; s < 384; ++s) {
        if (s == 256) {
            // ---------- xg2 = hT @ Wi2 + b2 (once), then swap weights to Wh2 ----------
            if (lane == 0 && !dead) {
                long it = 0;
                while (__hip_atomic_load(myflag, __ATOMIC_RELAXED, __HIP_MEMORY_SCOPE_AGENT) < 16 * 256) {
                    __builtin_amdgcn_s_sleep(2);
                    if (++it > (1L << 22)) { dead = true; break; }
                }
            }
            __builtin_amdgcn_fence(__ATOMIC_ACQUIRE, "agent");
            f32x4 acc[4];
            #pragma unroll
            for (int ct = 0; ct < 4; ++ct) acc[ct] = {0.f,0.f,0.f,0.f};
            const _Float16* hprev = hpp + 1 * NB * HD;   // h_255 lives in parity 1
            #pragma unroll
            for (int kk = 0; kk < 8; ++kk) {
                const int kb = kq + kk * 32 + lhi * 8;
                f16x8 a = *(const f16x8*)(hprev + brow * HD + kb);
                #pragma unroll
                for (int ct = 0; ct < 4; ++ct) {
                    const int col = ct * HD + u0 + l15;
                    f16x8 bb;
                    #pragma unroll
                    for (int e = 0; e < 8; ++e) bb[e] = (_Float16)Wi2[(kb + e) * G4 + col];
                    acc[ct] = __builtin_amdgcn_mfma_f32_16x16x32_f16(a, bb, acc[ct], 0, 0, 0);
                }
            }
            if (ks > 0) {
                #pragma unroll
                for (int ct = 0; ct < 4; ++ct)
                #pragma unroll
                for (int i = 0; i < 4; ++i)
                    parts[0][ks - 1][r][ct][l15][lhi * 4 + i] = acc[ct][i];
            }
            __syncthreads();
            if (ks == 0) {
                #pragma unroll
                for (int ct = 0; ct < 4; ++ct) {
                    #pragma unroll
                    for (int j = 0; j < 3; ++j)
                    #pragma unroll
                    for (int i = 0; i < 4; ++i)
                        acc[ct][i] += parts[0][j][r][ct][l15][lhi * 4 + i];
                    const float bv = b2[ct * HD + u0 + l15];
                    #pragma unroll
                    for (int i = 0; i < 4; ++i)
                        xg2s[r][ct][l15][lhi * 4 + i] = acc[ct][i] + bv;
                }
            }
            __syncthreads();   // protects parts[0] reuse by step 256 and xg2s reads
            // reload register weights with Wh2
            {
                const float* W = Wh2;
                #pragma unroll
                for (int kk = 0; kk < 8; ++kk)
                #pragma unroll
                for (int ct = 0; ct < 4; ++ct) {
                    const int col = ct * HD + u0 + l15;
                    const int kb  = kq + kk * 32 + lhi * 8;
                    f16x8 v;
                    #pragma unroll
                    for (int e = 0; e < 8; ++e) v[e] = (_Float16)W[(kb + e) * G4 + col];
                    wB[kk][ct] = v;
                }
            }
        }

        const int  par = s & 1;
        const bool l2  = (s >= 256);

        // ---- wait for h_{s-1} (this wave's K-quarter, this row-half) ----
        if (s > 0) {
            const int target = 16 * s;
            if (lane == 0 && !dead) {
                long it = 0;
                while (__hip_atomic_load(myflag, __ATOMIC_RELAXED, __HIP_MEMORY_SCOPE_AGENT) < target) {
                    __builtin_amdgcn_s_sleep(2);
                    if (++it > (1L << 22)) { dead = true; break; }
                }
            }
            __builtin_amdgcn_fence(__ATOMIC_ACQUIRE, "agent");
        }

        // ---- accumulator init: bias (L1) / xg2 (L2) on ks0, zero elsewhere ----
        f32x4 acc[4];
        if (ks == 0) {
            if (!l2) {
                #pragma unroll
                for (int ct = 0; ct < 4; ++ct)
                    acc[ct] = {bias4[ct], bias4[ct], bias4[ct], bias4[ct]};
            } else {
                #pragma unroll
                for (int ct = 0; ct < 4; ++ct)
                #pragma unroll
                for (int i = 0; i < 4; ++i)
                    acc[ct][i] = xg2s[r][ct][l15][lhi * 4 + i];
            }
        } else {
            #pragma unroll
            for (int ct = 0; ct < 4; ++ct) acc[ct] = {0.f,0.f,0.f,0.f};
        }

        // ---- h_{s-1} @ Wh (register-resident B) ----
        if (s > 0) {
            const _Float16* hprev = hpp + ((s + 1) & 1) * NB * HD;
            #pragma unroll
            for (int kk = 0; kk < 8; ++kk) {
                f16x8 a = *(const f16x8*)(hprev + brow * HD + kq + kk * 32 + lhi * 8);
                #pragma unroll
                for (int ct = 0; ct < 4; ++ct)
                    acc[ct] = __builtin_amdgcn_mfma_f32_16x16x32_f16(a, wB[kk][ct], acc[ct], 0, 0, 0);
            }
        }
        // ---- x_t @ Wi1 (layer 1, ks1 waves) ----
        if (!l2 && ks == 1) {
            const float* xp = x + (brow * TIN + s) * DIN;
            #pragma unroll
            for (int kk = 0; kk < 2; ++kk) {
                const int kb = kk * 32 + lhi * 8;
                f32x4 x0 = *(const f32x4*)(xp + kb);
                f32x4 x1 = *(const f32x4*)(xp + kb + 4);
                f16x8 a;
                #pragma unroll
                for (int e = 0; e < 4; ++e) { a[e] = (_Float16)x0[e]; a[e + 4] = (_Float16)x1[e]; }
                #pragma unroll
                for (int ct = 0; ct < 4; ++ct)
                    acc[ct] = __builtin_amdgcn_mfma_f32_16x16x32_f16(a, wX[kk][ct], acc[ct], 0, 0, 0);
            }
        }

        // ---- exchange K-quarter partials through LDS ----
        if (ks > 0) {
            #pragma unroll
            for (int ct = 0; ct < 4; ++ct)
            #pragma unroll
            for (int i = 0; i < 4; ++i)
                parts[par][ks - 1][r][ct][l15][lhi * 4 + i] = acc[ct][i];
        }
        __syncthreads();

        // ---- ks0: reduce + gates + state update + publish ----
        if (ks == 0) {
            #pragma unroll
            for (int ct = 0; ct < 4; ++ct)
            #pragma unroll
            for (int j = 0; j < 3; ++j)
            #pragma unroll
            for (int i = 0; i < 4; ++i)
                acc[ct][i] += parts[par][j][r][ct][l15][lhi * 4 + i];

            _Float16* hout = hpp + par * NB * HD;
            #pragma unroll
            for (int i = 0; i < 4; ++i) {
                const float ig = sigm(acc[0][i]);
                const float fg = sigm(acc[1][i]);
                const float gg = tanh_(acc[2][i]);
                const float og = sigm(acc[3][i]);
                const float cn = fg * cst[i] + ig * gg;
                cst[i] = cn;
                const float hn = og * tanh_(cn);
                const int row = g * 32 + r * 16 + lhi * 4 + i;
                hout[row * HD + u0 + l15] = (_Float16)hn;
                if (l2) hs2[((s - 256) * NB + row) * HD + u0 + l15] = (_Float16)hn;
            }
            __builtin_amdgcn_fence(__ATOMIC_RELEASE, "agent");
            if (lane == 0)
                __hip_atomic_fetch_add(outflag, 1, __ATOMIC_RELAXED, __HIP_MEMORY_SCOPE_AGENT);
        }
    }
}

// out[b][t][d] = hs2[t][b][:] @ Wlin + blin ; grid = 128 t x 2 d-halves
__global__ __launch_bounds__(512, 2)
void k_out(const unsigned char* __restrict__ ws, const float* __restrict__ blin,
           float* __restrict__ out)
{
    const _Float16* hs2 = (const _Float16*)(ws + HS2_OFF);
    const _Float16* wlt = (const _Float16*)(ws + WLT_OFF);
    const int tid  = threadIdx.x;
    const int lane = tid & 63;
    const int l15  = lane & 15, lhi = lane >> 4;
    const int w    = tid >> 6;
    const int wb   = w & 3, wd = w >> 2;
    const int t    = blockIdx.x >> 1;
    const int dh   = blockIdx.x & 1;
    const int b0   = wb * 32;
    const int d0   = dh * 64 + wd * 32;

    f32x4 acc[2][2];
    #pragma unroll
    for (int a_ = 0; a_ < 2; ++a_)
    #pragma unroll
    for (int b_ = 0; b_ < 2; ++b_) acc[a_][b_] = {0.f,0.f,0.f,0.f};

    #pragma unroll 4
    for (int kk = 0; kk < 32; ++kk) {
        const int kb = kk * 32 + lhi * 8;
        f16x8 a0 = *(const f16x8*)(hs2 + (t * NB + b0 + l15) * HD + kb);
        f16x8 a1 = *(const f16x8*)(hs2 + (t * NB + b0 + 16 + l15) * HD + kb);
        f16x8 q0 = *(const f16x8*)(wlt + (d0 + l15) * HD + kb);
        f16x8 q1 = *(const f16x8*)(wlt + (d0 + 16 + l15) * HD + kb);
        acc[0][0] = __builtin_amdgcn_mfma_f32_16x16x32_f16(a0, q0, acc[0][0], 0, 0, 0);
        acc[0][1] = __builtin_amdgcn_mfma_f32_16x16x32_f16(a0, q1, acc[0][1], 0, 0, 0);
        acc[1][0] = __builtin_amdgcn_mfma_f32_16x16x32_f16(a1, q0, acc[1][0], 0, 0, 0);
        acc[1][1] = __builtin_amdgcn_mfma_f32_16x16x32_f16(a1, q1, acc[1][1], 0, 0, 0);
    }
    #pragma unroll
    for (int bi = 0; bi < 2; ++bi)
    #pragma unroll
    for (int dj = 0; dj < 2; ++dj) {
        const int dcol = d0 + dj * 16 + l15;
        const float bv = blin[dcol];
        #pragma unroll
        for (int i = 0; i < 4; ++i) {
            const int row = b0 + bi * 16 + lhi * 4 + i;
            out[(row * TOUTC + t) * DOUTC + dcol] = acc[bi][dj][i] + bv;
        }
    }
}

extern "C" void kernel_launch(void* const* d_in, const int* in_sizes, int n_in,
                              void* d_out, int out_size, void* d_ws, size_t ws_size,
                              hipStream_t stream)
{
    const float* x    = (const float*)d_in[0];
    const float* Wi1  = (const float*)d_in[1];
    const float* Wh1  = (const float*)d_in[2];
    const float* b1   = (const float*)d_in[3];
    const float* Wi2  = (const float*)d_in[4];
    const float* Wh2  = (const float*)d_in[5];
    const float* b2   = (const float*)d_in[6];
    const float* Wlin = (const float*)d_in[7];
    const float* blin = (const float*)d_in[8];
    unsigned char* ws = (unsigned char*)d_ws;
    float* out = (float*)d_out;

    k_init<<<256, 256, 0, stream>>>(Wlin, ws);
    k_lstm<<<256, 512, 0, stream>>>(x, Wi1, Wh1, b1, Wi2, Wh2, b2, ws);
    k_out <<<256, 512, 0, stream>>>(ws, blin, out);
}

// Round 4
// 5272.959 us; speedup vs baseline: 2.4803x; 2.4803x over previous
//
#include <hip/hip_runtime.h>

#define NB   128
#define TIN  256
#define DIN  64
#define HD   1024
#define G4   4096
#define TOUTC 128
#define DOUTC 128

typedef _Float16 f16x8 __attribute__((ext_vector_type(8)));
typedef float    f32x4 __attribute__((ext_vector_type(4)));

// workspace layout (bytes)
#define FLAGS_OFF 0                         // 32 counters, stride 64B
#define HPP_OFF   4096                      // 2 * 128 * 1024 f16 = 524288
#define HS2_OFF   (4096 + 524288)           // 128*128*1024 f16 = 33554432
#define WLT_OFF   (HS2_OFF + 33554432)      // 128*1024 f16 = 262144

__device__ __forceinline__ float sigm(float z) {
    return 1.0f / (1.0f + __expf(-z));
}
__device__ __forceinline__ float tanh_(float z) {
    float e = __expf(2.0f * z);
    return 1.0f - 2.0f / (e + 1.0f);
}

// 8x coherent (LLC-direct) 16B loads from one base address, single waitcnt.
// sc0 sc1 => bypass L1 and L2, read from the device coherence point; no
// buffer_inv needed. Early-clobber outputs so the address pair stays intact.
__device__ __forceinline__ void load_h8(const _Float16* p, f16x8 av[8]) {
    asm volatile(
        "global_load_dwordx4 %0, %8, off sc0 sc1\n\t"
        "global_load_dwordx4 %1, %8, off offset:64 sc0 sc1\n\t"
        "global_load_dwordx4 %2, %8, off offset:128 sc0 sc1\n\t"
        "global_load_dwordx4 %3, %8, off offset:192 sc0 sc1\n\t"
        "global_load_dwordx4 %4, %8, off offset:256 sc0 sc1\n\t"
        "global_load_dwordx4 %5, %8, off offset:320 sc0 sc1\n\t"
        "global_load_dwordx4 %6, %8, off offset:384 sc0 sc1\n\t"
        "global_load_dwordx4 %7, %8, off offset:448 sc0 sc1\n\t"
        "s_waitcnt vmcnt(0)"
        : "=&v"(av[0]), "=&v"(av[1]), "=&v"(av[2]), "=&v"(av[3]),
          "=&v"(av[4]), "=&v"(av[5]), "=&v"(av[6]), "=&v"(av[7])
        : "v"(p)
        : "memory");
}

__global__ void k_init(const float* __restrict__ Wlin, unsigned char* __restrict__ ws)
{
    int tid = blockIdx.x * blockDim.x + threadIdx.x;
    if (tid < 32) ((int*)(ws + FLAGS_OFF))[tid * 16] = 0;
    _Float16* wlt = (_Float16*)(ws + WLT_OFF);
    for (int i = tid; i < DOUTC * HD; i += gridDim.x * blockDim.x) {
        int d = i >> 10, k = i & 1023;
        wlt[i] = (_Float16)Wlin[k * DOUTC + d];   // WlinT[d][k]
    }
}

// Persistent recurrent kernel: 256 WGs x 512 threads, 1 WG/CU.
// group g = batches [32g,32g+32); WG p owns hidden units [16p,16p+16)
// wave (r,ks): r = row half (16 batches), ks = K-quarter. Wh frags in VGPRs.
__global__ __launch_bounds__(512, 2)
void k_lstm(const float* __restrict__ x,   const float* __restrict__ Wi1,
            const float* __restrict__ Wh1, const float* __restrict__ b1,
            const float* __restrict__ Wi2, const float* __restrict__ Wh2,
            const float* __restrict__ b2,  unsigned char* __restrict__ ws)
{
    int* flags      = (int*)(ws + FLAGS_OFF);
    _Float16* hpp   = (_Float16*)(ws + HPP_OFF);
    _Float16* hs2   = (_Float16*)(ws + HS2_OFF);

    const int tid  = threadIdx.x;
    const int lane = tid & 63;
    const int w    = tid >> 6;
    const int r    = w & 1;
    const int ks   = w >> 1;
    const int gid  = blockIdx.x;
    const int g    = gid >> 6;
    const int p    = gid & 63;
    const int u0   = p << 4;
    const int l15  = lane & 15;
    const int lhi  = lane >> 4;
    const int brow = g * 32 + r * 16 + l15;   // batch row for MFMA operands
    const int kq   = ks << 8;                 // K-quarter base

    __shared__ float parts[2][3][2][4][16][17];   // [parity][ks-1][r][gate][unit][row]
    __shared__ float xg2s[2][4][16][17];          // [r][gate][unit][row]

    f16x8 wB[8][4];      // Wh frags: [kk][gate], K-quarter split per wave
    f16x8 wX[2][4];      // Wi1 frags (ks==1 waves only)
    float bias4[4];
    f32x4 cst = {0.f, 0.f, 0.f, 0.f};

    // ---- load Wh1 fragments into registers ----
    {
        const float* W = Wh1;
        #pragma unroll
        for (int kk = 0; kk < 8; ++kk)
        #pragma unroll
        for (int ct = 0; ct < 4; ++ct) {
            const int col = ct * HD + u0 + l15;
            const int kb  = kq + kk * 32 + lhi * 8;
            f16x8 v;
            #pragma unroll
            for (int e = 0; e < 8; ++e) v[e] = (_Float16)W[(kb + e) * G4 + col];
            wB[kk][ct] = v;
        }
    }
    if (ks == 1) {
        #pragma unroll
        for (int kk = 0; kk < 2; ++kk)
        #pragma unroll
        for (int ct = 0; ct < 4; ++ct) {
            const int col = ct * HD + u0 + l15;
            const int kb  = kk * 32 + lhi * 8;
            f16x8 v;
            #pragma unroll
            for (int e = 0; e < 8; ++e) v[e] = (_Float16)Wi1[(kb + e) * G4 + col];
            wX[kk][ct] = v;
        }
    }
    if (ks == 0) {
        #pragma unroll
        for (int ct = 0; ct < 4; ++ct) bias4[ct] = b1[ct * HD + u0 + l15];
    }

    int* myflag  = &flags[((g * 2 + r) * 4 + ks) * 16];        // consumed
    int* outflag = &flags[((g * 2 + r) * 4 + (p >> 4)) * 16];  // produced (ks0)

    bool dead = false;   // spin bailout latch (anti-hang insurance)

    #pragma unroll 1
    for (int s = 0; s < 384; ++s) {
        if (s == 256) {
            // ---------- xg2 = hT @ Wi2 + b2 (once), swap weights to Wh2 ----------
            if (lane == 0 && !dead) {
                long it = 0;
                while (__hip_atomic_load(myflag, __ATOMIC_RELAXED, __HIP_MEMORY_SCOPE_AGENT) < 16 * 256) {
                    __builtin_amdgcn_s_sleep(1);
                    if (++it > (1L << 22)) { dead = true; break; }
                }
            }
            f32x4 acc[4];
            #pragma unroll
            for (int ct = 0; ct < 4; ++ct) acc[ct] = {0.f,0.f,0.f,0.f};
            const _Float16* hprev = hpp + 1 * NB * HD;   // h_255 in parity 1
            f16x8 av[8];
            load_h8(hprev + brow * HD + kq + lhi * 8, av);   // per-lane fragment base
            #pragma unroll
            for (int kk = 0; kk < 8; ++kk) {
                const int kb = kq + kk * 32 + lhi * 8;
                #pragma unroll
                for (int ct = 0; ct < 4; ++ct) {
                    const int col = ct * HD + u0 + l15;
                    f16x8 bb;
                    #pragma unroll
                    for (int e = 0; e < 8; ++e) bb[e] = (_Float16)Wi2[(kb + e) * G4 + col];
                    acc[ct] = __builtin_amdgcn_mfma_f32_16x16x32_f16(av[kk], bb, acc[ct], 0, 0, 0);
                }
            }
            if (ks > 0) {
                #pragma unroll
                for (int ct = 0; ct < 4; ++ct)
                #pragma unroll
                for (int i = 0; i < 4; ++i)
                    parts[0][ks - 1][r][ct][l15][lhi * 4 + i] = acc[ct][i];
            }
            __syncthreads();
            if (ks == 0) {
                #pragma unroll
                for (int ct = 0; ct < 4; ++ct) {
                    #pragma unroll
                    for (int j = 0; j < 3; ++j)
                    #pragma unroll
                    for (int i = 0; i < 4; ++i)
                        acc[ct][i] += parts[0][j][r][ct][l15][lhi * 4 + i];
                    const float bv = b2[ct * HD + u0 + l15];
                    #pragma unroll
                    for (int i = 0; i < 4; ++i)
                        xg2s[r][ct][l15][lhi * 4 + i] = acc[ct][i] + bv;
                }
            }
            __syncthreads();   // protects parts[0] reuse and xg2s reads
            // reload register weights with Wh2
            {
                const float* W = Wh2;
                #pragma unroll
                for (int kk = 0; kk < 8; ++kk)
                #pragma unroll
                for (int ct = 0; ct < 4; ++ct) {
                    const int col = ct * HD + u0 + l15;
                    const int kb  = kq + kk * 32 + lhi * 8;
                    f16x8 v;
                    #pragma unroll
                    for (int e = 0; e < 8; ++e) v[e] = (_Float16)W[(kb + e) * G4 + col];
                    wB[kk][ct] = v;
                }
            }
        }

        const int  par = s & 1;
        const bool l2  = (s >= 256);

        // ---- wait for h_{s-1} (this wave's K-quarter, this row-half) ----
        if (s > 0) {
            const int target = 16 * s;
            if (lane == 0 && !dead) {
                long it = 0;
                while (__hip_atomic_load(myflag, __ATOMIC_RELAXED, __HIP_MEMORY_SCOPE_AGENT) < target) {
                    __builtin_amdgcn_s_sleep(1);
                    if (++it > (1L << 22)) { dead = true; break; }
                }
            }
        }

        // ---- accumulator init: bias (L1) / xg2 (L2) on ks0, zero elsewhere ----
        f32x4 acc[4];
        if (ks == 0) {
            if (!l2) {
                #pragma unroll
                for (int ct = 0; ct < 4; ++ct)
                    acc[ct] = {bias4[ct], bias4[ct], bias4[ct], bias4[ct]};
            } else {
                #pragma unroll
                for (int ct = 0; ct < 4; ++ct)
                #pragma unroll
                for (int i = 0; i < 4; ++i)
                    acc[ct][i] = xg2s[r][ct][l15][lhi * 4 + i];
            }
        } else {
            #pragma unroll
            for (int ct = 0; ct < 4; ++ct) acc[ct] = {0.f,0.f,0.f,0.f};
        }

        // ---- h_{s-1} @ Wh (register-resident B, LLC-coherent A) ----
        if (s > 0) {
            const _Float16* hprev = hpp + ((s + 1) & 1) * NB * HD;
            f16x8 av[8];
            load_h8(hprev + brow * HD + kq + lhi * 8, av);
            #pragma unroll
            for (int kk = 0; kk < 8; ++kk) {
                #pragma unroll
                for (int ct = 0; ct < 4; ++ct)
                    acc[ct] = __builtin_amdgcn_mfma_f32_16x16x32_f16(av[kk], wB[kk][ct], acc[ct], 0, 0, 0);
            }
        }
        // ---- x_t @ Wi1 (layer 1, ks1 waves) ----
        if (!l2 && ks == 1) {
            const float* xp = x + (brow * TIN + s) * DIN;
            #pragma unroll
            for (int kk = 0; kk < 2; ++kk) {
                const int kb = kk * 32 + lhi * 8;
                f32x4 x0 = *(const f32x4*)(xp + kb);
                f32x4 x1 = *(const f32x4*)(xp + kb + 4);
                f16x8 a;
                #pragma unroll
                for (int e = 0; e < 4; ++e) { a[e] = (_Float16)x0[e]; a[e + 4] = (_Float16)x1[e]; }
                #pragma unroll
                for (int ct = 0; ct < 4; ++ct)
                    acc[ct] = __builtin_amdgcn_mfma_f32_16x16x32_f16(a, wX[kk][ct], acc[ct], 0, 0, 0);
            }
        }

        // ---- exchange K-quarter partials through LDS ----
        if (ks > 0) {
            #pragma unroll
            for (int ct = 0; ct < 4; ++ct)
            #pragma unroll
            for (int i = 0; i < 4; ++i)
                parts[par][ks - 1][r][ct][l15][lhi * 4 + i] = acc[ct][i];
        }
        __syncthreads();

        // ---- ks0: reduce + gates + state update + publish ----
        if (ks == 0) {
            #pragma unroll
            for (int ct = 0; ct < 4; ++ct)
            #pragma unroll
            for (int j = 0; j < 3; ++j)
            #pragma unroll
            for (int i = 0; i < 4; ++i)
                acc[ct][i] += parts[par][j][r][ct][l15][lhi * 4 + i];

            _Float16* hout = hpp + par * NB * HD;
            unsigned hb[4];
            #pragma unroll
            for (int i = 0; i < 4; ++i) {
                const float ig = sigm(acc[0][i]);
                const float fg = sigm(acc[1][i]);
                const float gg = tanh_(acc[2][i]);
                const float og = sigm(acc[3][i]);
                const float cn = fg * cst[i] + ig * gg;
                cst[i] = cn;
                const float hn = og * tanh_(cn);
                const _Float16 hf = (_Float16)hn;
                hb[i] = (unsigned)__builtin_bit_cast(unsigned short, hf);
                const int row = g * 32 + r * 16 + lhi * 4 + i;
                if (l2) hs2[((s - 256) * NB + row) * HD + u0 + l15] = hf;
            }
            const int rbase = g * 32 + r * 16 + lhi * 4;
            _Float16* p01 = hout + rbase * HD + u0 + l15;
            _Float16* p23 = p01 + 2 * HD;
            // write-through stores to the coherence point + completion wait,
            // then the flag increment is safely ordered after the data.
            asm volatile(
                "global_store_short %0, %2, off sc0 sc1\n\t"
                "global_store_short %0, %3, off offset:2048 sc0 sc1\n\t"
                "global_store_short %1, %4, off sc0 sc1\n\t"
                "global_store_short %1, %5, off offset:2048 sc0 sc1\n\t"
                "s_waitcnt vmcnt(0)"
                :
                : "v"(p01), "v"(p23), "v"(hb[0]), "v"(hb[1]), "v"(hb[2]), "v"(hb[3])
                : "memory");
            if (lane == 0)
                __hip_atomic_fetch_add(outflag, 1, __ATOMIC_RELAXED, __HIP_MEMORY_SCOPE_AGENT);
        }
    }
}

// out[b][t][d] = hs2[t][b][:] @ Wlin + blin ; grid = 128 t x 2 d-halves
__global__ __launch_bounds__(512, 2)
void k_out(const unsigned char* __restrict__ ws, const float* __restrict__ blin,
           float* __restrict__ out)
{
    const _Float16* hs2 = (const _Float16*)(ws + HS2_OFF);
    const _Float16* wlt = (const _Float16*)(ws + WLT_OFF);
    const int tid  = threadIdx.x;
    const int lane = tid & 63;
    const int l15  = lane & 15, lhi = lane >> 4;
    const int w    = tid >> 6;
    const int wb   = w & 3, wd = w >> 2;
    const int t    = blockIdx.x >> 1;
    const int dh   = blockIdx.x & 1;
    const int b0   = wb * 32;
    const int d0   = dh * 64 + wd * 32;

    f32x4 acc[2][2];
    #pragma unroll
    for (int a_ = 0; a_ < 2; ++a_)
    #pragma unroll
    for (int b_ = 0; b_ < 2; ++b_) acc[a_][b_] = {0.f,0.f,0.f,0.f};

    #pragma unroll 4
    for (int kk = 0; kk < 32; ++kk) {
        const int kb = kk * 32 + lhi * 8;
        f16x8 a0 = *(const f16x8*)(hs2 + (t * NB + b0 + l15) * HD + kb);
        f16x8 a1 = *(const f16x8*)(hs2 + (t * NB + b0 + 16 + l15) * HD + kb);
        f16x8 q0 = *(const f16x8*)(wlt + (d0 + l15) * HD + kb);
        f16x8 q1 = *(const f16x8*)(wlt + (d0 + 16 + l15) * HD + kb);
        acc[0][0] = __builtin_amdgcn_mfma_f32_16x16x32_f16(a0, q0, acc[0][0], 0, 0, 0);
        acc[0][1] = __builtin_amdgcn_mfma_f32_16x16x32_f16(a0, q1, acc[0][1], 0, 0, 0);
        acc[1][0] = __builtin_amdgcn_mfma_f32_16x16x32_f16(a1, q0, acc[1][0], 0, 0, 0);
        acc[1][1] = __builtin_amdgcn_mfma_f32_16x16x32_f16(a1, q1, acc[1][1], 0, 0, 0);
    }
    #pragma unroll
    for (int bi = 0; bi < 2; ++bi)
    #pragma unroll
    for (int dj = 0; dj < 2; ++dj) {
        const int dcol = d0 + dj * 16 + l15;
        const float bv = blin[dcol];
        #pragma unroll
        for (int i = 0; i < 4; ++i) {
            const int row = b0 + bi * 16 + lhi * 4 + i;
            out[(row * TOUTC + t) * DOUTC + dcol] = acc[bi][dj][i] + bv;
        }
    }
}

extern "C" void kernel_launch(void* const* d_in, const int* in_sizes, int n_in,
                              void* d_out, int out_size, void* d_ws, size_t ws_size,
                              hipStream_t stream)
{
    const float* x    = (const float*)d_in[0];
    const float* Wi1  = (const float*)d_in[1];
    const float* Wh1  = (const float*)d_in[2];
    const float* b1   = (const float*)d_in[3];
    const float* Wi2  = (const float*)d_in[4];
    const float* Wh2  = (const float*)d_in[5];
    const float* b2   = (const float*)d_in[6];
    const float* Wlin = (const float*)d_in[7];
    const float* blin = (const float*)d_in[8];
    unsigned char* ws = (unsigned char*)d_ws;
    float* out = (float*)d_out;

    k_init<<<256, 256, 0, stream>>>(Wlin, ws);
    k_lstm<<<256, 512, 0, stream>>>(x, Wi1, Wh1, b1, Wi2, Wh2, b2, ws);
    k_out <<<256, 512, 0, stream>>>(ws, blin, out);
}